// Round 5
// baseline (177.486 us; speedup 1.0000x reference)
//
#include <hip/hip_runtime.h>
#include <hip/hip_bf16.h>
#include <math.h>

// Problem constants (fixed by setup_inputs)
#define BATCH 512
#define NADV  16
#define NROWS (BATCH*NADV)     // 8192
#define DS    32
#define DO    32
#define DIM   64               // DS + DO
#define HID   128
#define WCOLS (DIM*HID)        // 8192 columns of hw2
#define LSTR  136              // padded f16 LDS row stride (2-way bank aliasing)
#define DG    8                // d-values per k_hyper block (8 d-groups total)
#define PACK_BLOCKS 276

typedef _Float16 half8 __attribute__((ext_vector_type(8)));
typedef float floatx4 __attribute__((ext_vector_type(4)));

__device__ inline void async_ld16(void* lds, const void* g) {
    __builtin_amdgcn_global_load_lds(
        (const __attribute__((address_space(1))) void*)g,
        (__attribute__((address_space(3))) void*)lds, 16, 0, 0);
}

// ---------------------------------------------------------------------------
// Kernel PREP (fused): blocks [0,276) pack weights into MFMA-native f16
// chunks (coalesced 512-B row reads via 32x128 LDS tile); blocks [276,788)
// build x + h = relu(x@hw1+hb1). Block 0 also zeroes the finisher counters.
// Packed layout: chunk(ct,kt)[lane*8+e] = W[kt*32+(lane>>4)*8+e][ct*16+(lane&15)]
// so a wave's B-fragment load is ONE contiguous 1 KB burst.
// ---------------------------------------------------------------------------
__global__ __launch_bounds__(256)
void k_prep(const float* __restrict__ obs, const float* __restrict__ latent,
            const float* __restrict__ hw1, const float* __restrict__ hb1,
            const float* __restrict__ hw2, const float* __restrict__ vw1,
            const float* __restrict__ vw2, const float* __restrict__ aw1,
            const float* __restrict__ aw2,
            float* __restrict__ xbuf, _Float16* __restrict__ hf,
            _Float16* __restrict__ w2p, _Float16* __restrict__ vw1p,
            _Float16* __restrict__ vw2p, _Float16* __restrict__ aw1p,
            _Float16* __restrict__ aw2p, unsigned* __restrict__ counters) {
    __shared__ __align__(16) float smem[32 * 132];   // 16.9 KB, pad 132 vs banks
    int b = blockIdx.x;
    int tid = threadIdx.x;
    if (b < PACK_BLOCKS) {
        if (b == 0 && tid < 64) counters[tid] = 0;   // finisher counters
        const float* src; _Float16* dst; int N, Kt, jb, kt;
        if (b < 256)      { src = hw2; dst = w2p;  N = WCOLS; Kt = 4; jb = b >> 2; kt = b & 3; }
        else if (b < 260) { src = vw1; dst = vw1p; N = HID;   Kt = 4; jb = 0; kt = b - 256; }
        else if (b < 264) { src = vw2; dst = vw2p; N = HID;   Kt = 4; jb = 0; kt = b - 260; }
        else if (b < 272) { src = aw1; dst = aw1p; N = HID;   Kt = 8; jb = 0; kt = b - 264; }
        else              { src = aw2; dst = aw2p; N = HID;   Kt = 4; jb = 0; kt = b - 272; }
        // coalesced read: 32 k-rows x 128 j-cols (512 B contiguous per row)
        for (int i = tid; i < 32 * 32; i += 256) {
            int r = i >> 5, c4 = (i & 31) * 4;
            *(float4*)&smem[r * 132 + c4] =
                *(const float4*)(src + (size_t)(kt * 32 + r) * N + jb * 128 + c4);
        }
        __syncthreads();
        // write 8 chunks (ctl 0..7), each 1 KB, fully contiguous stores
        for (int i = tid; i < 8 * 64; i += 256) {
            int ctl = i >> 6, lane = i & 63;
            int ct = jb * 8 + ctl;
            int rbase = (lane >> 4) * 8, cc = ctl * 16 + (lane & 15);
            half8 v;
#pragma unroll
            for (int e = 0; e < 8; ++e) v[e] = (_Float16)smem[(rbase + e) * 132 + cc];
            *(half8*)(dst + ((size_t)ct * Kt + kt) * 512 + lane * 8) = v;
        }
    } else {
        // input_h: 16 rows, h = relu(x @ hw1 + hb1)
        int n0 = (b - PACK_BLOCKS) * 16;
        float* xs = smem;   // [16][DIM]
        for (int idx = tid; idx < 16 * DIM; idx += 256) {
            int r = idx >> 6, d = idx & 63;
            int n = n0 + r;
            // reference pairs obs[n % B] with latent_flat[n] (torch .repeat
            // tiles the batch dim; reshape(-1,DO) row-major) — exact.
            float v = (d < DS) ? obs[(n & (BATCH - 1)) * DS + d]
                               : latent[(size_t)n * DO + (d - DS)];
            xs[r * DIM + d] = v;
            xbuf[(size_t)n * DIM + d] = v;
        }
        __syncthreads();
        int j = tid & 127, hh = tid >> 7;   // hh: rows hh*8..+8
        float acc[8];
        float bb = hb1[j];
#pragma unroll
        for (int r = 0; r < 8; ++r) acc[r] = bb;
        for (int d = 0; d < DIM; ++d) {
            float w = hw1[d * HID + j];
#pragma unroll
            for (int r = 0; r < 8; ++r)
                acc[r] = fmaf(xs[(hh * 8 + r) * DIM + d], w, acc[r]);
        }
#pragma unroll
        for (int r = 0; r < 8; ++r)
            hf[(size_t)(n0 + hh * 8 + r) * HID + j] = (_Float16)fmaxf(acc[r], 0.f);
    }
}

// ---------------------------------------------------------------------------
// Kernel B: LDS-staged tiled MFMA GEMM + fused epilogue + fence-counter
// finisher. Block = 128 rows x 8 d's. The 8th block to finish a row-tile
// sums the 8 fp32 partials, applies tanh -> embf (f16), and computes the
// 8 batch means (row-tile = 8 complete batches). Cross-XCD visibility via
// __threadfence (release) + device-scope atomicAdd + __threadfence (acquire).
// ---------------------------------------------------------------------------
__global__ __launch_bounds__(512, 4)
void k_hyper_mfma(const float* __restrict__ xbuf, const _Float16* __restrict__ hf,
                  const _Float16* __restrict__ w2p, const float* __restrict__ hb2,
                  float* __restrict__ partials, _Float16* __restrict__ embf,
                  _Float16* __restrict__ emeanf, unsigned* __restrict__ counters) {
    __shared__ __align__(16) _Float16 Bs[8][4][512];  // 32 KB: [tile][kt][lane*8+e]
    __shared__ float xs[128][9];                      // pad 9: conflict-free
    __shared__ float bias_s[DG * HID];
    __shared__ int flag;
    int b  = blockIdx.x;
    int rb = b & 63;        // row-tile:  rows [rb*128, +128)
    int dg = b >> 6;        // d-group:   d in [dg*8, +8)
    int tid = threadIdx.x;
    int wave = tid >> 6, lane = tid & 63;
    int l15 = lane & 15, quad = lane >> 4;
    int row0 = rb * 128;

    for (int i = tid; i < 128 * 8; i += 512) {
        int r = i >> 3, c = i & 7;
        xs[r][c] = xbuf[(size_t)(row0 + r) * DIM + dg * 8 + c];
    }
    for (int i = tid; i < DG * HID; i += 512)
        bias_s[i] = hb2[dg * (DG * HID) + i];

    half8 af[4];
    {
        const _Float16* arow = hf + (size_t)(row0 + wave * 16 + l15) * HID;
#pragma unroll
        for (int ks = 0; ks < 4; ++ks)
            af[ks] = *(const half8*)(arow + ks * 32 + quad * 8);
    }

    float emb_acc[8][4];
#pragma unroll
    for (int ct2 = 0; ct2 < 8; ++ct2)
#pragma unroll
        for (int reg = 0; reg < 4; ++reg) emb_acc[ct2][reg] = 0.f;

    for (int d8 = 0; d8 < DG; ++d8) {
        {   // stage B (32 KB): wave w stages tile w as 4 x 1 KB async bursts
            int ctg = (dg * DG + d8) * 8 + wave;
            const _Float16* src = w2p + (size_t)ctg * 2048 + lane * 8;
            _Float16* dst = &Bs[wave][0][0];
#pragma unroll
            for (int kt = 0; kt < 4; ++kt)
                async_ld16(dst + kt * 512, src + kt * 512);
        }
        __syncthreads();

        float xv[4];
#pragma unroll
        for (int reg = 0; reg < 4; ++reg)
            xv[reg] = xs[wave * 16 + quad * 4 + reg][d8];

#pragma unroll
        for (int ct2 = 0; ct2 < 8; ++ct2) {
            float bb = bias_s[d8 * HID + ct2 * 16 + l15];
            floatx4 acc = {bb, bb, bb, bb};
#pragma unroll
            for (int ks = 0; ks < 4; ++ks) {
                half8 bfr = *(const half8*)&Bs[ct2][ks][lane * 8];
                acc = __builtin_amdgcn_mfma_f32_16x16x32_f16(af[ks], bfr, acc, 0, 0, 0);
            }
#pragma unroll
            for (int reg = 0; reg < 4; ++reg)
                emb_acc[ct2][reg] = fmaf(xv[reg], fmaxf(acc[reg], 0.f),
                                         emb_acc[ct2][reg]);
        }
        __syncthreads();
    }

    // write fp32 partial for this d-group
    float* pout = partials + (size_t)dg * NROWS * HID
                + (size_t)(row0 + wave * 16) * HID;
#pragma unroll
    for (int ct2 = 0; ct2 < 8; ++ct2)
#pragma unroll
        for (int reg = 0; reg < 4; ++reg)
            pout[(size_t)(quad * 4 + reg) * HID + ct2 * 16 + l15] = emb_acc[ct2][reg];

    // ---- fence-counter finisher ----
    __syncthreads();              // all waves' stores drained (vmcnt at barrier)
    if (tid == 0) {
        __threadfence();          // release: write back to device scope
        unsigned old = atomicAdd(&counters[rb], 1u);
        flag = (old == 7);
    }
    __syncthreads();
    if (!flag) return;
    __threadfence();              // acquire: invalidate stale cached lines

    _Float16* et = &Bs[0][0][0];  // reuse 32 KB LDS as emb f16 [128][128]
    for (int i = tid; i < 128 * HID; i += 512) {
        int r = i >> 7, c = i & 127;
        size_t off = (size_t)(row0 + r) * HID + c;
        float s = 0.f;
#pragma unroll
        for (int p = 0; p < 8; ++p)
            s += partials[(size_t)p * NROWS * HID + off];
        float e = tanhf(s);
        et[i] = (_Float16)e;
        embf[off] = (_Float16)e;
    }
    __syncthreads();
    for (int i = tid; i < 8 * HID; i += 512) {
        int bi = i >> 7, c = i & 127;
        float s = 0.f;
#pragma unroll
        for (int rr = 0; rr < 16; ++rr)
            s += (float)et[(bi * 16 + rr) * HID + c];
        emeanf[(size_t)(rb * 8 + bi) * HID + c] = (_Float16)(s * (1.f / 16));
    }
}

// ---------------------------------------------------------------------------
// Kernel T (fused tail), 512 blocks x 16 rows (1 softmax group each):
//   vals = relu(relu(emb@vw1+b)@vw2+b)                 [MFMA, regs]
//   scores = relu(relu([emb|mean]@aw1+b)@aw2+b)@aw3+b  [MFMA + dot]
//   att = softmax over the 16 rows; out[g] = sum_a att*vals (direct store)
// ---------------------------------------------------------------------------
__global__ __launch_bounds__(512, 4)
void k_tail(const _Float16* __restrict__ embf, const _Float16* __restrict__ emeanf,
            const _Float16* __restrict__ vw1p, const float* __restrict__ vb1,
            const _Float16* __restrict__ vw2p, const float* __restrict__ vb2,
            const _Float16* __restrict__ aw1p, const float* __restrict__ ab1,
            const _Float16* __restrict__ aw2p, const float* __restrict__ ab2,
            const float* __restrict__ aw3, const float* __restrict__ ab3,
            float* __restrict__ out) {
    __shared__ _Float16 embs[16][LSTR];
    __shared__ _Float16 means[16][LSTR];
    __shared__ _Float16 tAs[16][LSTR];
    __shared__ _Float16 tBs[16][LSTR];
    __shared__ float scr[16][32];
    __shared__ float satt[16];
    __shared__ float att[16];
    int g = blockIdx.x;       // batch 0..511
    int n0 = g * 16;
    int tid = threadIdx.x;
    int wave = tid >> 6, lane = tid & 63, l15 = lane & 15, quad = lane >> 4;
    int ct = wave;            // wave owns col-tile ct of 8

    {   // stage emb rows + mean rows (512 half8 loads = 1/thread)
        int m = tid >> 8, r = (tid >> 4) & 15, c8 = (tid & 15) * 8;
        if (m == 0)
            *(half8*)&embs[r][c8] = *(const half8*)(embf + (size_t)(n0 + r) * HID + c8);
        else
            // mean_rep[n] = emb_mean[n % 512] (torch .repeat tiling) — exact.
            *(half8*)&means[r][c8] =
                *(const half8*)(emeanf + (size_t)((n0 & 511) + r) * HID + c8);
    }
    __syncthreads();

    half8 av[4], amean[4];
#pragma unroll
    for (int ks = 0; ks < 4; ++ks) {
        av[ks]    = *(const half8*)&embs[l15][ks * 32 + quad * 8];
        amean[ks] = *(const half8*)&means[l15][ks * 32 + quad * 8];
    }

    // ---- v1: t1 = relu(emb @ vw1 + vb1) ----
    floatx4 acc;
    {
        float bb = vb1[ct * 16 + l15];
        acc = (floatx4){bb, bb, bb, bb};
    }
#pragma unroll
    for (int ks = 0; ks < 4; ++ks) {
        half8 bfr = *(const half8*)(vw1p + ((size_t)ct * 4 + ks) * 512 + lane * 8);
        acc = __builtin_amdgcn_mfma_f32_16x16x32_f16(av[ks], bfr, acc, 0, 0, 0);
    }
#pragma unroll
    for (int reg = 0; reg < 4; ++reg)
        tAs[quad * 4 + reg][ct * 16 + l15] = (_Float16)fmaxf(acc[reg], 0.f);
    __syncthreads();

    half8 at[4];
#pragma unroll
    for (int ks = 0; ks < 4; ++ks)
        at[ks] = *(const half8*)&tAs[l15][ks * 32 + quad * 8];

    // ---- v2: vals = relu(t1 @ vw2 + vb2), kept in registers ----
    floatx4 vacc;
    {
        float bb = vb2[ct * 16 + l15];
        vacc = (floatx4){bb, bb, bb, bb};
    }
#pragma unroll
    for (int ks = 0; ks < 4; ++ks) {
        half8 bfr = *(const half8*)(vw2p + ((size_t)ct * 4 + ks) * 512 + lane * 8);
        vacc = __builtin_amdgcn_mfma_f32_16x16x32_f16(at[ks], bfr, vacc, 0, 0, 0);
    }

    // ---- a1: ta1 = relu([emb|mean] @ aw1 + ab1), K=256 ----
    floatx4 aacc;
    {
        float bb = ab1[ct * 16 + l15];
        aacc = (floatx4){bb, bb, bb, bb};
    }
#pragma unroll
    for (int ks = 0; ks < 8; ++ks) {
        half8 bfr = *(const half8*)(aw1p + ((size_t)ct * 8 + ks) * 512 + lane * 8);
        half8 a = (ks < 4) ? av[ks] : amean[ks - 4];
        aacc = __builtin_amdgcn_mfma_f32_16x16x32_f16(a, bfr, aacc, 0, 0, 0);
    }
#pragma unroll
    for (int reg = 0; reg < 4; ++reg)
        tBs[quad * 4 + reg][ct * 16 + l15] = (_Float16)fmaxf(aacc[reg], 0.f);
    __syncthreads();

    half8 aa[4];
#pragma unroll
    for (int ks = 0; ks < 4; ++ks)
        aa[ks] = *(const half8*)&tBs[l15][ks * 32 + quad * 8];

    // ---- a2: t2 = relu(ta1 @ aw2 + ab2) -> tAs ----
    floatx4 a2acc;
    {
        float bb = ab2[ct * 16 + l15];
        a2acc = (floatx4){bb, bb, bb, bb};
    }
#pragma unroll
    for (int ks = 0; ks < 4; ++ks) {
        half8 bfr = *(const half8*)(aw2p + ((size_t)ct * 4 + ks) * 512 + lane * 8);
        a2acc = __builtin_amdgcn_mfma_f32_16x16x32_f16(aa[ks], bfr, a2acc, 0, 0, 0);
    }
    __syncthreads();   // everyone done reading tAs (at) from v1 stage
#pragma unroll
    for (int reg = 0; reg < 4; ++reg)
        tAs[quad * 4 + reg][ct * 16 + l15] = (_Float16)fmaxf(a2acc[reg], 0.f);
    __syncthreads();

    // ---- scores: s[r] = t2[r,:] . aw3 + ab3 ----
    {
        int r = tid >> 5, ch = tid & 31;
        float p = 0.f;
#pragma unroll
        for (int k = 0; k < 4; ++k)
            p += (float)tAs[r][ch * 4 + k] * aw3[ch * 4 + k];
        scr[r][ch] = p;
    }
    __syncthreads();
    if (tid < 16) {
        float s = ab3[0];
#pragma unroll
        for (int ch = 0; ch < 32; ++ch) s += scr[tid][ch];
        satt[tid] = s;
    }
    __syncthreads();
    if (tid < 16) {
        float m = -1e30f;
#pragma unroll
        for (int a = 0; a < 16; ++a) m = fmaxf(m, satt[a]);
        float S = 0.f;
#pragma unroll
        for (int a = 0; a < 16; ++a) S += expf(satt[a] - m);
        att[tid] = expf(satt[tid] - m) / S;
    }
    __syncthreads();

    // ---- weighted sum: out[g, col] = sum_a att[a] * vals[a, col] ----
    {
        float p = 0.f;
#pragma unroll
        for (int reg = 0; reg < 4; ++reg)
            p += att[quad * 4 + reg] * fmaxf(vacc[reg], 0.f);
        p += __shfl_xor(p, 16, 64);
        p += __shfl_xor(p, 32, 64);
        if (quad == 0) out[(size_t)g * HID + ct * 16 + l15] = p;
    }
}

// ---------------------------------------------------------------------------
extern "C" void kernel_launch(void* const* d_in, const int* in_sizes, int n_in,
                              void* d_out, int out_size, void* d_ws, size_t ws_size,
                              hipStream_t stream) {
    const float* obs = (const float*)d_in[0];
    const float* lat = (const float*)d_in[1];
    const float* hw1 = (const float*)d_in[2];
    const float* hb1 = (const float*)d_in[3];
    const float* hw2 = (const float*)d_in[4];
    const float* hb2 = (const float*)d_in[5];
    const float* vw1 = (const float*)d_in[6];
    const float* vb1 = (const float*)d_in[7];
    const float* vw2 = (const float*)d_in[8];
    const float* vb2 = (const float*)d_in[9];
    const float* aw1 = (const float*)d_in[10];
    const float* ab1 = (const float*)d_in[11];
    const float* aw2 = (const float*)d_in[12];
    const float* ab2 = (const float*)d_in[13];
    const float* aw3 = (const float*)d_in[14];
    const float* ab3 = (const float*)d_in[15];
    float* out = (float*)d_out;

    char* ws = (char*)d_ws;
    float*     xbuf   = (float*)ws;     ws += (size_t)NROWS * DIM * 4;     // 2 MB
    _Float16*  hf     = (_Float16*)ws;  ws += (size_t)NROWS * HID * 2;     // 2 MB
    _Float16*  w2p    = (_Float16*)ws;  ws += (size_t)WCOLS * HID * 2;     // 2 MB
    _Float16*  embf   = (_Float16*)ws;  ws += (size_t)NROWS * HID * 2;     // 2 MB
    _Float16*  emeanf = (_Float16*)ws;  ws += (size_t)BATCH * HID * 2;     // 128 KB
    _Float16*  vw1p   = (_Float16*)ws;  ws += (size_t)HID * HID * 2;       // 32 KB
    _Float16*  vw2p   = (_Float16*)ws;  ws += (size_t)HID * HID * 2;
    _Float16*  aw1p   = (_Float16*)ws;  ws += (size_t)2 * HID * HID * 2;   // 64 KB
    _Float16*  aw2p   = (_Float16*)ws;  ws += (size_t)HID * HID * 2;
    float*     partials = (float*)ws;   ws += (size_t)8 * NROWS * HID * 4; // 32 MB
    unsigned*  counters = (unsigned*)ws; ws += 64 * sizeof(unsigned);

    hipLaunchKernelGGL(k_prep, dim3(PACK_BLOCKS + NROWS / 16), dim3(256), 0, stream,
                       obs, lat, hw1, hb1, hw2, vw1, vw2, aw1, aw2,
                       xbuf, hf, w2p, vw1p, vw2p, aw1p, aw2p, counters);
    hipLaunchKernelGGL(k_hyper_mfma, dim3(512), dim3(512), 0, stream,
                       xbuf, hf, w2p, hb2, partials, embf, emeanf, counters);
    hipLaunchKernelGGL(k_tail, dim3(BATCH), dim3(512), 0, stream,
                       embf, emeanf, vw1p, vb1, vw2p, vb2,
                       aw1p, ab1, aw2p, ab2, aw3, ab3, out);
}

// Round 6
// 132.092 us; speedup vs baseline: 1.3436x; 1.3436x over previous
//
#include <hip/hip_runtime.h>
#include <hip/hip_bf16.h>
#include <math.h>

// Problem constants (fixed by setup_inputs)
#define BATCH 512
#define NADV  16
#define NROWS (BATCH*NADV)     // 8192
#define DS    32
#define DO    32
#define DIM   64               // DS + DO
#define HID   128
#define WCOLS (DIM*HID)        // 8192 columns of hw2
#define LSTR  136              // padded f16 LDS row stride (2-way bank aliasing)
#define PACK_BLOCKS 276

typedef _Float16 half8 __attribute__((ext_vector_type(8)));
typedef float floatx4 __attribute__((ext_vector_type(4)));

__device__ inline void async_ld16(void* lds, const void* g) {
    __builtin_amdgcn_global_load_lds(
        (const __attribute__((address_space(1))) void*)g,
        (__attribute__((address_space(3))) void*)lds, 16, 0, 0);
}

// ---------------------------------------------------------------------------
// Kernel PREP (fused): blocks [0,276) pack weights into MFMA-native f16
// chunks (coalesced 512-B row reads via LDS tile); blocks [276,788) build
// h = relu(x@hw1+hb1) (x formed in LDS from obs/latent; not materialized).
// Packed layout: chunk(ct,kt)[lane*8+e] = W[kt*32+(lane>>4)*8+e][ct*16+(lane&15)]
// so a wave's B-fragment load is ONE contiguous 1 KB burst.
// ---------------------------------------------------------------------------
__global__ __launch_bounds__(256)
void k_prep(const float* __restrict__ obs, const float* __restrict__ latent,
            const float* __restrict__ hw1, const float* __restrict__ hb1,
            const float* __restrict__ hw2, const float* __restrict__ vw1,
            const float* __restrict__ vw2, const float* __restrict__ aw1,
            const float* __restrict__ aw2,
            _Float16* __restrict__ hf,
            _Float16* __restrict__ w2p, _Float16* __restrict__ vw1p,
            _Float16* __restrict__ vw2p, _Float16* __restrict__ aw1p,
            _Float16* __restrict__ aw2p) {
    __shared__ __align__(16) float smem[32 * 132];   // 16.9 KB
    int b = blockIdx.x;
    int tid = threadIdx.x;
    if (b < PACK_BLOCKS) {
        const float* src; _Float16* dst; int N, Kt, jb, kt;
        if (b < 256)      { src = hw2; dst = w2p;  N = WCOLS; Kt = 4; jb = b >> 2; kt = b & 3; }
        else if (b < 260) { src = vw1; dst = vw1p; N = HID;   Kt = 4; jb = 0; kt = b - 256; }
        else if (b < 264) { src = vw2; dst = vw2p; N = HID;   Kt = 4; jb = 0; kt = b - 260; }
        else if (b < 272) { src = aw1; dst = aw1p; N = HID;   Kt = 8; jb = 0; kt = b - 264; }
        else              { src = aw2; dst = aw2p; N = HID;   Kt = 4; jb = 0; kt = b - 272; }
        // coalesced read: 32 k-rows x 128 j-cols (512 B contiguous per row)
        for (int i = tid; i < 32 * 32; i += 256) {
            int r = i >> 5, c4 = (i & 31) * 4;
            *(float4*)&smem[r * 132 + c4] =
                *(const float4*)(src + (size_t)(kt * 32 + r) * N + jb * 128 + c4);
        }
        __syncthreads();
        // write 8 chunks (ctl 0..7), each 1 KB, fully contiguous stores
        for (int i = tid; i < 8 * 64; i += 256) {
            int ctl = i >> 6, lane = i & 63;
            int ct = jb * 8 + ctl;
            int rbase = (lane >> 4) * 8, cc = ctl * 16 + (lane & 15);
            half8 v;
#pragma unroll
            for (int e = 0; e < 8; ++e) v[e] = (_Float16)smem[(rbase + e) * 132 + cc];
            *(half8*)(dst + ((size_t)ct * Kt + kt) * 512 + lane * 8) = v;
        }
    } else {
        // input_h: 16 rows, h = relu(x @ hw1 + hb1)
        int n0 = (b - PACK_BLOCKS) * 16;
        float* xs = smem;   // [16][DIM]
        for (int idx = tid; idx < 16 * DIM; idx += 256) {
            int r = idx >> 6, d = idx & 63;
            int n = n0 + r;
            // reference pairs obs[n % B] with latent_flat[n] (torch .repeat
            // tiles the batch dim; reshape(-1,DO) row-major) — exact.
            xs[r * DIM + d] = (d < DS) ? obs[(n & (BATCH - 1)) * DS + d]
                                       : latent[(size_t)n * DO + (d - DS)];
        }
        __syncthreads();
        int j = tid & 127, hh = tid >> 7;   // hh: rows hh*8..+8
        float acc[8];
        float bb = hb1[j];
#pragma unroll
        for (int r = 0; r < 8; ++r) acc[r] = bb;
        for (int d = 0; d < DIM; ++d) {
            float w = hw1[d * HID + j];
#pragma unroll
            for (int r = 0; r < 8; ++r)
                acc[r] = fmaf(xs[(hh * 8 + r) * DIM + d], w, acc[r]);
        }
#pragma unroll
        for (int r = 0; r < 8; ++r)
            hf[(size_t)(n0 + hh * 8 + r) * HID + j] = (_Float16)fmaxf(acc[r], 0.f);
    }
}

// ---------------------------------------------------------------------------
// Kernel B: block = 128 rows x 16 emb-cols x ALL 64 d  ->  d-reduction is
// block-local in 4 regs/lane; no partials, no fences. Grid = 64 rt x 8 jt
// (jt = b&7 aligns each jt's shared 256 KB B-set with one XCD's L2).
// Per d8-chunk: async-stage 8 B-tiles (32 KB) to LDS, 8-wave reuse, 32 MFMA.
// Epilogue: emb = tanh(acc) -> embf f16; wave = 1 batch -> emeanf direct.
// ---------------------------------------------------------------------------
__global__ __launch_bounds__(512, 4)
void k_hyper_mfma(const float* __restrict__ obs, const float* __restrict__ latent,
                  const _Float16* __restrict__ hf, const _Float16* __restrict__ w2p,
                  const float* __restrict__ hb2,
                  _Float16* __restrict__ embf, _Float16* __restrict__ emeanf) {
    __shared__ __align__(16) _Float16 Bs[8][4][512];  // 32 KB: [dtile][kt][lane*8+e]
    __shared__ float xs[128][68];                     // 34 KB; stride 68: 2-way alias only
    __shared__ float bias_s[64 * 16];                 // 4 KB
    int b  = blockIdx.x;
    int jt = b & 7;          // emb col-tile (16 cols) — XCD-aligned B reuse
    int rt = b >> 3;         // row-tile: rows [rt*128, +128)
    int n0 = rt * 128;
    int j0 = jt * 16;
    int tid = threadIdx.x;
    int wave = tid >> 6, lane = tid & 63;
    int l15 = lane & 15, quad = lane >> 4;

    // stage x[128][64] (obs[n%512] ++ latent[n]) and bias slice
    for (int i = tid; i < 128 * 16; i += 512) {
        int r = i >> 4, c4 = (i & 15) * 4;
        float4 v;
        if (c4 < DS) v = *(const float4*)(obs + ((n0 + r) & (BATCH - 1)) * DS + c4);
        else         v = *(const float4*)(latent + (size_t)(n0 + r) * DO + (c4 - DS));
        *(float4*)&xs[r][c4] = v;
    }
    for (int i = tid; i < 64 * 16; i += 512)
        bias_s[i] = hb2[(i >> 4) * HID + j0 + (i & 15)];

    // A fragments: wave w owns rows [n0+w*16, +16) (= batch rt*8+w)
    half8 af[4];
    {
        const _Float16* arow = hf + (size_t)(n0 + wave * 16 + l15) * HID;
#pragma unroll
        for (int ks = 0; ks < 4; ++ks)
            af[ks] = *(const half8*)(arow + ks * 32 + quad * 8);
    }

    float emb_acc[4] = {0.f, 0.f, 0.f, 0.f};

    for (int d8 = 0; d8 < 8; ++d8) {
        {   // stage B: wave w stages d-tile (d8*8+w)'s chunk as 4 x 1 KB bursts
            int ct = (d8 * 8 + wave) * 8 + jt;
            const _Float16* src = w2p + (size_t)ct * 2048 + lane * 8;
            _Float16* dst = &Bs[wave][0][0];
#pragma unroll
            for (int kt = 0; kt < 4; ++kt)
                async_ld16(dst + kt * 512, src + kt * 512);
        }
        __syncthreads();   // staging done (also covers xs/bias on iter 0)

#pragma unroll
        for (int dd = 0; dd < 8; ++dd) {
            int d = d8 * 8 + dd;
            float bb = bias_s[d * 16 + l15];
            floatx4 acc = {bb, bb, bb, bb};
#pragma unroll
            for (int ks = 0; ks < 4; ++ks) {
                half8 bfr = *(const half8*)&Bs[dd][ks][lane * 8];
                acc = __builtin_amdgcn_mfma_f32_16x16x32_f16(af[ks], bfr, acc, 0, 0, 0);
            }
            // D: row = wave*16 + quad*4 + reg, col = j0 + l15
#pragma unroll
            for (int reg = 0; reg < 4; ++reg) {
                float xv = xs[wave * 16 + quad * 4 + reg][d];
                emb_acc[reg] = fmaf(xv, fmaxf(acc[reg], 0.f), emb_acc[reg]);
            }
        }
        __syncthreads();   // done consuming Bs; safe to restage
    }

    // epilogue: tanh -> embf; wave = one batch -> column means direct
    float e[4];
#pragma unroll
    for (int reg = 0; reg < 4; ++reg) {
        e[reg] = tanhf(emb_acc[reg]);
        embf[(size_t)(n0 + wave * 16 + quad * 4 + reg) * HID + j0 + l15] =
            (_Float16)e[reg];
    }
    float s = e[0] + e[1] + e[2] + e[3];
    s += __shfl_xor(s, 16, 64);
    s += __shfl_xor(s, 32, 64);
    if (quad == 0)
        emeanf[(size_t)(rt * 8 + wave) * HID + j0 + l15] = (_Float16)(s * (1.f / 16));
}

// ---------------------------------------------------------------------------
// Kernel T (fused tail), 512 blocks x 16 rows (1 softmax group each):
//   vals = relu(relu(emb@vw1+b)@vw2+b)                 [MFMA, regs]
//   scores = relu(relu([emb|mean]@aw1+b)@aw2+b)@aw3+b  [MFMA + dot]
//   att = softmax over the 16 rows; out[g] = sum_a att*vals (direct store)
// ---------------------------------------------------------------------------
__global__ __launch_bounds__(512, 4)
void k_tail(const _Float16* __restrict__ embf, const _Float16* __restrict__ emeanf,
            const _Float16* __restrict__ vw1p, const float* __restrict__ vb1,
            const _Float16* __restrict__ vw2p, const float* __restrict__ vb2,
            const _Float16* __restrict__ aw1p, const float* __restrict__ ab1,
            const _Float16* __restrict__ aw2p, const float* __restrict__ ab2,
            const float* __restrict__ aw3, const float* __restrict__ ab3,
            float* __restrict__ out) {
    __shared__ _Float16 embs[16][LSTR];
    __shared__ _Float16 means[16][LSTR];
    __shared__ _Float16 tAs[16][LSTR];
    __shared__ _Float16 tBs[16][LSTR];
    __shared__ float scr[16][32];
    __shared__ float satt[16];
    __shared__ float att[16];
    int g = blockIdx.x;       // batch 0..511
    int n0 = g * 16;
    int tid = threadIdx.x;
    int wave = tid >> 6, lane = tid & 63, l15 = lane & 15, quad = lane >> 4;
    int ct = wave;            // wave owns col-tile ct of 8

    {   // stage emb rows + mean rows (512 half8 loads = 1/thread)
        int m = tid >> 8, r = (tid >> 4) & 15, c8 = (tid & 15) * 8;
        if (m == 0)
            *(half8*)&embs[r][c8] = *(const half8*)(embf + (size_t)(n0 + r) * HID + c8);
        else
            // mean_rep[n] = emb_mean[n % 512] (torch .repeat tiling) — exact.
            *(half8*)&means[r][c8] =
                *(const half8*)(emeanf + (size_t)((n0 & 511) + r) * HID + c8);
    }
    __syncthreads();

    half8 av[4], amean[4];
#pragma unroll
    for (int ks = 0; ks < 4; ++ks) {
        av[ks]    = *(const half8*)&embs[l15][ks * 32 + quad * 8];
        amean[ks] = *(const half8*)&means[l15][ks * 32 + quad * 8];
    }

    // ---- v1: t1 = relu(emb @ vw1 + vb1) ----
    floatx4 acc;
    {
        float bb = vb1[ct * 16 + l15];
        acc = (floatx4){bb, bb, bb, bb};
    }
#pragma unroll
    for (int ks = 0; ks < 4; ++ks) {
        half8 bfr = *(const half8*)(vw1p + ((size_t)ct * 4 + ks) * 512 + lane * 8);
        acc = __builtin_amdgcn_mfma_f32_16x16x32_f16(av[ks], bfr, acc, 0, 0, 0);
    }
#pragma unroll
    for (int reg = 0; reg < 4; ++reg)
        tAs[quad * 4 + reg][ct * 16 + l15] = (_Float16)fmaxf(acc[reg], 0.f);
    __syncthreads();

    half8 at[4];
#pragma unroll
    for (int ks = 0; ks < 4; ++ks)
        at[ks] = *(const half8*)&tAs[l15][ks * 32 + quad * 8];

    // ---- v2: vals = relu(t1 @ vw2 + vb2), kept in registers ----
    floatx4 vacc;
    {
        float bb = vb2[ct * 16 + l15];
        vacc = (floatx4){bb, bb, bb, bb};
    }
#pragma unroll
    for (int ks = 0; ks < 4; ++ks) {
        half8 bfr = *(const half8*)(vw2p + ((size_t)ct * 4 + ks) * 512 + lane * 8);
        vacc = __builtin_amdgcn_mfma_f32_16x16x32_f16(at[ks], bfr, vacc, 0, 0, 0);
    }

    // ---- a1: ta1 = relu([emb|mean] @ aw1 + ab1), K=256 ----
    floatx4 aacc;
    {
        float bb = ab1[ct * 16 + l15];
        aacc = (floatx4){bb, bb, bb, bb};
    }
#pragma unroll
    for (int ks = 0; ks < 8; ++ks) {
        half8 bfr = *(const half8*)(aw1p + ((size_t)ct * 8 + ks) * 512 + lane * 8);
        half8 a = (ks < 4) ? av[ks] : amean[ks - 4];
        aacc = __builtin_amdgcn_mfma_f32_16x16x32_f16(a, bfr, aacc, 0, 0, 0);
    }
#pragma unroll
    for (int reg = 0; reg < 4; ++reg)
        tBs[quad * 4 + reg][ct * 16 + l15] = (_Float16)fmaxf(aacc[reg], 0.f);
    __syncthreads();

    half8 aa[4];
#pragma unroll
    for (int ks = 0; ks < 4; ++ks)
        aa[ks] = *(const half8*)&tBs[l15][ks * 32 + quad * 8];

    // ---- a2: t2 = relu(ta1 @ aw2 + ab2) -> tAs ----
    floatx4 a2acc;
    {
        float bb = ab2[ct * 16 + l15];
        a2acc = (floatx4){bb, bb, bb, bb};
    }
#pragma unroll
    for (int ks = 0; ks < 4; ++ks) {
        half8 bfr = *(const half8*)(aw2p + ((size_t)ct * 4 + ks) * 512 + lane * 8);
        a2acc = __builtin_amdgcn_mfma_f32_16x16x32_f16(aa[ks], bfr, a2acc, 0, 0, 0);
    }
    __syncthreads();   // everyone done reading tAs (at) from v1 stage
#pragma unroll
    for (int reg = 0; reg < 4; ++reg)
        tAs[quad * 4 + reg][ct * 16 + l15] = (_Float16)fmaxf(a2acc[reg], 0.f);
    __syncthreads();

    // ---- scores: s[r] = t2[r,:] . aw3 + ab3 ----
    {
        int r = tid >> 5, ch = tid & 31;
        float p = 0.f;
#pragma unroll
        for (int k = 0; k < 4; ++k)
            p += (float)tAs[r][ch * 4 + k] * aw3[ch * 4 + k];
        scr[r][ch] = p;
    }
    __syncthreads();
    if (tid < 16) {
        float s = ab3[0];
#pragma unroll
        for (int ch = 0; ch < 32; ++ch) s += scr[tid][ch];
        satt[tid] = s;
    }
    __syncthreads();
    if (tid < 16) {
        float m = -1e30f;
#pragma unroll
        for (int a = 0; a < 16; ++a) m = fmaxf(m, satt[a]);
        float S = 0.f;
#pragma unroll
        for (int a = 0; a < 16; ++a) S += expf(satt[a] - m);
        att[tid] = expf(satt[tid] - m) / S;
    }
    __syncthreads();

    // ---- weighted sum: out[g, col] = sum_a att[a] * vals[a, col] ----
    {
        float p = 0.f;
#pragma unroll
        for (int reg = 0; reg < 4; ++reg)
            p += att[quad * 4 + reg] * fmaxf(vacc[reg], 0.f);
        p += __shfl_xor(p, 16, 64);
        p += __shfl_xor(p, 32, 64);
        if (quad == 0) out[(size_t)g * HID + ct * 16 + l15] = p;
    }
}

// ---------------------------------------------------------------------------
extern "C" void kernel_launch(void* const* d_in, const int* in_sizes, int n_in,
                              void* d_out, int out_size, void* d_ws, size_t ws_size,
                              hipStream_t stream) {
    const float* obs = (const float*)d_in[0];
    const float* lat = (const float*)d_in[1];
    const float* hw1 = (const float*)d_in[2];
    const float* hb1 = (const float*)d_in[3];
    const float* hw2 = (const float*)d_in[4];
    const float* hb2 = (const float*)d_in[5];
    const float* vw1 = (const float*)d_in[6];
    const float* vb1 = (const float*)d_in[7];
    const float* vw2 = (const float*)d_in[8];
    const float* vb2 = (const float*)d_in[9];
    const float* aw1 = (const float*)d_in[10];
    const float* ab1 = (const float*)d_in[11];
    const float* aw2 = (const float*)d_in[12];
    const float* ab2 = (const float*)d_in[13];
    const float* aw3 = (const float*)d_in[14];
    const float* ab3 = (const float*)d_in[15];
    float* out = (float*)d_out;

    char* ws = (char*)d_ws;
    _Float16*  hf     = (_Float16*)ws;  ws += (size_t)NROWS * HID * 2;     // 2 MB
    _Float16*  w2p    = (_Float16*)ws;  ws += (size_t)WCOLS * HID * 2;     // 2 MB
    _Float16*  embf   = (_Float16*)ws;  ws += (size_t)NROWS * HID * 2;     // 2 MB
    _Float16*  emeanf = (_Float16*)ws;  ws += (size_t)BATCH * HID * 2;     // 128 KB
    _Float16*  vw1p   = (_Float16*)ws;  ws += (size_t)HID * HID * 2;       // 32 KB
    _Float16*  vw2p   = (_Float16*)ws;  ws += (size_t)HID * HID * 2;
    _Float16*  aw1p   = (_Float16*)ws;  ws += (size_t)2 * HID * HID * 2;   // 64 KB
    _Float16*  aw2p   = (_Float16*)ws;  ws += (size_t)HID * HID * 2;

    hipLaunchKernelGGL(k_prep, dim3(PACK_BLOCKS + NROWS / 16), dim3(256), 0, stream,
                       obs, lat, hw1, hb1, hw2, vw1, vw2, aw1, aw2,
                       hf, w2p, vw1p, vw2p, aw1p, aw2p);
    hipLaunchKernelGGL(k_hyper_mfma, dim3(512), dim3(512), 0, stream,
                       obs, lat, hf, w2p, hb2, embf, emeanf);
    hipLaunchKernelGGL(k_tail, dim3(BATCH), dim3(512), 0, stream,
                       embf, emeanf, vw1p, vb1, vw2p, vb2,
                       aw1p, ab1, aw2p, ab2, aw3, ab3, out);
}